// Round 1
// baseline (724.075 us; speedup 1.0000x reference)
//
#include <hip/hip_runtime.h>

// ParallelTransportUnpool:
//   out[dst[e], 0, ch, :] = x[c, 0, ch, :]
//   out[dst[e], 1, ch, :] = x[c, 1, ch, :] * conj(connection[e])   (complex mul)
// where c = index of src[e] in sorted unpool_nodes (binary search).
// edge_dst is a permutation -> every output row written exactly once.

__global__ __launch_bounds__(256) void ParallelTransportUnpool_87582973100651_kernel(
    const float4* __restrict__ x,          // (N_COARSE, 2, 128, 2) viewed as 128 float4/row
    const float2* __restrict__ conn,       // (N_FINE, 2)
    const int*    __restrict__ nodes,      // (N_COARSE,) sorted
    const int*    __restrict__ edge_src,   // (N_FINE,)
    const int*    __restrict__ edge_dst,   // (N_FINE,)
    float4*       __restrict__ out,        // (N_FINE, 2, 128, 2) as 128 float4/row
    int n_fine, int n_coarse)
{
    // 2 edges per 256-thread block; 128 lanes per edge (one float4 each).
    int e = blockIdx.x * 2 + (threadIdx.x >> 7);
    if (e >= n_fine) return;
    int lane = threadIdx.x & 127;

    int s = edge_src[e];
    int d = edge_dst[e];

    // binary search for s in nodes[0..n_coarse) -- uniform across the edge's lanes
    int lo = 0, hi = n_coarse - 1;
    while (lo < hi) {
        int mid = (lo + hi) >> 1;
        if (nodes[mid] < s) lo = mid + 1; else hi = mid;
    }
    int c = lo;

    float4 v = x[(size_t)c * 128 + lane];

    if (lane >= 64) {   // group 1: multiply by conj(connection[e]) -- wave-uniform branch
        float2 b = conn[e];
        float br = b.x;
        float bi = -b.y;
        float4 r;
        r.x = v.x * br - v.y * bi;
        r.y = v.x * bi + v.y * br;
        r.z = v.z * br - v.w * bi;
        r.w = v.z * bi + v.w * br;
        v = r;
    }

    out[(size_t)d * 128 + lane] = v;
}

extern "C" void kernel_launch(void* const* d_in, const int* in_sizes, int n_in,
                              void* d_out, int out_size, void* d_ws, size_t ws_size,
                              hipStream_t stream) {
    const float4* x     = (const float4*)d_in[0];
    const float2* conn  = (const float2*)d_in[1];
    const int*    nodes = (const int*)d_in[2];
    const int*    edges = (const int*)d_in[3];   // (2, N_FINE): row0 = src, row1 = dst
    // d_in[4] = num_nodes scalar (unused; derived from sizes)

    const int n_coarse = in_sizes[2];
    const int n_fine   = in_sizes[3] / 2;

    const int* edge_src = edges;
    const int* edge_dst = edges + n_fine;

    float4* out = (float4*)d_out;

    int blocks = (n_fine + 1) / 2;   // 2 edges per block
    ParallelTransportUnpool_87582973100651_kernel<<<blocks, 256, 0, stream>>>(
        x, conn, nodes, edge_src, edge_dst, out, n_fine, n_coarse);
}